// Round 1
// baseline (534.350 us; speedup 1.0000x reference)
//
#include <hip/hip_runtime.h>
#include <hip/hip_bf16.h>

// Problem constants
#define BATCH 64
#define CIN   128
#define HIN   56
#define WIN   56
#define COUT  256
#define KSZ   3
#define OHP   54   // output H (valid)
#define OWP   54   // output W (valid)
#define KDIM  (CIN * KSZ * KSZ)   // 1152

typedef short bf16x8 __attribute__((ext_vector_type(8)));
typedef float f32x4  __attribute__((ext_vector_type(4)));

static __device__ __forceinline__ unsigned short f2bf(float f) {
    // round-to-nearest-even bf16 (inputs finite)
    unsigned v = __float_as_uint(f);
    v += 0x7FFFu + ((v >> 16) & 1u);
    return (unsigned short)(v >> 16);
}

// ---------------- kernel 1: max |w| reduction ----------------
__global__ __launch_bounds__(256) void maxabs_kernel(const float* __restrict__ w,
                                                     unsigned* __restrict__ out, int n) {
    float m = 0.f;
    for (int i = blockIdx.x * blockDim.x + threadIdx.x; i < n; i += gridDim.x * blockDim.x)
        m = fmaxf(m, fabsf(w[i]));
    for (int off = 32; off > 0; off >>= 1)
        m = fmaxf(m, __shfl_down(m, off));
    __shared__ float red[4];
    if ((threadIdx.x & 63) == 0) red[threadIdx.x >> 6] = m;
    __syncthreads();
    if (threadIdx.x == 0) {
        m = fmaxf(fmaxf(red[0], red[1]), fmaxf(red[2], red[3]));
        atomicMax(out, __float_as_uint(m));  // non-negative floats: uint order == float order
    }
}

// ---------------- kernel 2: ternary quantize + repack to [co][kk*128+ci] bf16 ----------------
__global__ __launch_bounds__(256) void quant_kernel(const float* __restrict__ w,
                                                    const float* __restrict__ wp,
                                                    const float* __restrict__ wn,
                                                    const unsigned* __restrict__ maxbits,
                                                    unsigned short* __restrict__ qw) {
    int idx = blockIdx.x * 256 + threadIdx.x;   // grid covers exactly 294912
    float t = 0.05f * __uint_as_float(maxbits[0]);
    float p = fabsf(wp[0]), nn = fabsf(wn[0]);
    float v = w[idx];
    float q = (v > t) ? p : ((v < -t) ? -nn : 0.0f);
    int co  = idx / KDIM;
    int rem = idx - co * KDIM;
    int ci  = rem / 9;
    int kk  = rem - ci * 9;            // kh*3+kw
    qw[co * KDIM + kk * CIN + ci] = f2bf(q);
}

// ---------------- kernel 3: x fp32 NCHW -> bf16 NHWC (x_t[b][h][w][ci]) ----------------
__global__ __launch_bounds__(256) void cast_nhwc_kernel(const float* __restrict__ x,
                                                        unsigned* __restrict__ xt_u32) {
    int b = blockIdx.x / HIN;
    int h = blockIdx.x - b * HIN;
    __shared__ float xs[CIN][WIN + 1];
    for (int idx = threadIdx.x; idx < CIN * WIN; idx += 256) {
        int ci = idx / WIN;
        int w_ = idx - ci * WIN;
        xs[ci][w_] = x[(((size_t)b * CIN + ci) * HIN + h) * WIN + w_];
    }
    __syncthreads();
    // write: for each w, 128 ci contiguous (as 64 packed uints)
    for (int idx = threadIdx.x; idx < WIN * 64; idx += 256) {
        int w_ = idx >> 6;
        int cp = (idx & 63) * 2;
        unsigned lo = f2bf(xs[cp][w_]);
        unsigned hi = f2bf(xs[cp + 1][w_]);
        xt_u32[((size_t)(b * HIN + h) * WIN + w_) * 64 + (idx & 63)] = lo | (hi << 16);
    }
}

// ---------------- kernel 4: implicit-GEMM MFMA conv ----------------
// tiles: BM=128 (co), BN=128 (spatial: 8 oh x 16 ow), BK=32
// grid = 2 (mt) * 64 (b) * 7 (oht) * 4 (owt) = 3584 blocks, 256 threads (4 waves)
__global__ __launch_bounds__(256, 2) void conv_mfma_kernel(const unsigned short* __restrict__ xt,
                                                           const unsigned short* __restrict__ qw,
                                                           const float* __restrict__ bias,
                                                           float* __restrict__ out) {
    int id  = blockIdx.x;
    int owt = id & 3;  id >>= 2;
    int oht = id % 7;  id /= 7;
    int b   = id & 63;
    int mt  = id >> 6;
    int oh0 = oht * 8, ow0 = owt * 16;

    __shared__ __align__(16) unsigned short As[128][40];  // [m][k] pad +8
    __shared__ __align__(16) unsigned short Bs[128][40];  // [n][k] pad +8

    int t    = threadIdx.x;
    int wave = t >> 6, lane = t & 63;
    int wm   = wave >> 1, wcol = wave & 1;
    int quad = lane >> 4, r16 = lane & 15;

    // staging coords: thread t handles row t>>1, 16 consecutive k at (t&1)*16
    int srow = t >> 1;
    int skb  = (t & 1) * 16;
    int bohl = srow >> 4, bowl = srow & 15;

    f32x4 acc[4][4] = {};

    for (int kc = 0; kc < 36; ++kc) {
        int slice = kc >> 2;           // kh*3+kw
        int kh = slice / 3;
        int kw = slice - kh * 3;
        int ci0 = (kc & 3) * 32;

        // ---- A stage: qw[mt*128+srow][kc*32 + skb .. +15] ----
        {
            const int4* src = (const int4*)(qw + (size_t)(mt * 128 + srow) * KDIM + kc * 32 + skb);
            int4 v0 = src[0];
            int4 v1 = src[1];
            *(int4*)&As[srow][skb]     = v0;
            *(int4*)&As[srow][skb + 8] = v1;
        }
        // ---- B stage: x_t[b][oh0+bohl+kh][ow0+bowl+kw][ci0+skb .. +15] ----
        {
            int h = oh0 + bohl + kh;
            int w_ = ow0 + bowl + kw;
            int4 v0 = {0, 0, 0, 0}, v1 = {0, 0, 0, 0};
            if (h < HIN && w_ < WIN) {
                const int4* src = (const int4*)(xt + ((size_t)(b * HIN + h) * WIN + w_) * CIN + ci0 + skb);
                v0 = src[0];
                v1 = src[1];
            }
            *(int4*)&Bs[srow][skb]     = v0;
            *(int4*)&Bs[srow][skb + 8] = v1;
        }
        __syncthreads();

        bf16x8 af[4], bfr[4];
#pragma unroll
        for (int i = 0; i < 4; ++i)
            af[i] = *(const bf16x8*)&As[wm * 64 + i * 16 + r16][quad * 8];
#pragma unroll
        for (int j = 0; j < 4; ++j)
            bfr[j] = *(const bf16x8*)&Bs[wcol * 64 + j * 16 + r16][quad * 8];
#pragma unroll
        for (int i = 0; i < 4; ++i)
#pragma unroll
            for (int j = 0; j < 4; ++j)
                acc[i][j] = __builtin_amdgcn_mfma_f32_16x16x32_bf16(af[i], bfr[j], acc[i][j], 0, 0, 0);
        __syncthreads();
    }

    // ---- epilogue: D row m = quad*4+r, col n = r16 ----
#pragma unroll
    for (int i = 0; i < 4; ++i) {
        int co_base = mt * 128 + wm * 64 + i * 16 + quad * 4;
#pragma unroll
        for (int j = 0; j < 4; ++j) {
            int oh = oh0 + wcol * 4 + j;
            int ow = ow0 + r16;
            if (oh < OHP && ow < OWP) {
#pragma unroll
                for (int r = 0; r < 4; ++r) {
                    int co = co_base + r;
                    out[(((size_t)b * COUT + co) * OHP + oh) * OWP + ow] = acc[i][j][r] + bias[co];
                }
            }
        }
    }
}

extern "C" void kernel_launch(void* const* d_in, const int* in_sizes, int n_in,
                              void* d_out, int out_size, void* d_ws, size_t ws_size,
                              hipStream_t stream) {
    const float* x      = (const float*)d_in[0];
    const float* weight = (const float*)d_in[1];
    const float* bias   = (const float*)d_in[2];
    const float* wp     = (const float*)d_in[3];
    const float* wn     = (const float*)d_in[4];
    float* out          = (float*)d_out;

    // ws layout: [0,4)   maxabs bits (zeroed)
    //            [256, 256+589824)            qw bf16 [256][1152]
    //            [590080, 590080+51380224)    x_t bf16 NHWC [64][56][56][128]
    unsigned*       ws_max = (unsigned*)d_ws;
    unsigned short* qw     = (unsigned short*)((char*)d_ws + 256);
    unsigned short* xt     = (unsigned short*)((char*)d_ws + 590080);

    hipMemsetAsync(d_ws, 0, 4, stream);

    maxabs_kernel<<<256, 256, 0, stream>>>(weight, ws_max, COUT * KDIM);
    quant_kernel<<<(COUT * KDIM) / 256, 256, 0, stream>>>(weight, wp, wn, ws_max, qw);
    cast_nhwc_kernel<<<BATCH * HIN, 256, 0, stream>>>(x, (unsigned*)xt);
    conv_mfma_kernel<<<2 * BATCH * 7 * 4, 256, 0, stream>>>(xt, qw, bias, out);
}

// Round 2
// 451.262 us; speedup vs baseline: 1.1841x; 1.1841x over previous
//
#include <hip/hip_runtime.h>
#include <hip/hip_bf16.h>

// Problem constants
#define BATCH 64
#define CIN   128
#define HIN   56
#define WIN   56
#define COUT  256
#define KSZ   3
#define OHP   54
#define OWP   54
#define NSPAT (OHP * OWP)          // 2916 flat spatial outputs per batch
#define NTILES 23                  // ceil(2916/128)
#define KDIM  (CIN * KSZ * KSZ)    // 1152

typedef short bf16x8 __attribute__((ext_vector_type(8)));
typedef float f32x4  __attribute__((ext_vector_type(4)));

static __device__ __forceinline__ unsigned short f2bf(float f) {
    unsigned v = __float_as_uint(f);
    v += 0x7FFFu + ((v >> 16) & 1u);
    return (unsigned short)(v >> 16);
}

// async 16B global -> LDS (DMA path, no VGPR roundtrip). LDS dest is
// wave-uniform base + lane*16; global src is per-lane.
static __device__ __forceinline__ void gl_lds16(const void* g, void* l) {
    __builtin_amdgcn_global_load_lds(
        (const __attribute__((address_space(1))) void*)g,
        (__attribute__((address_space(3))) void*)l, 16, 0, 0);
}

// ---------------- kernel 1: max |w| reduction ----------------
__global__ __launch_bounds__(256) void maxabs_kernel(const float* __restrict__ w,
                                                     unsigned* __restrict__ out, int n) {
    float m = 0.f;
    for (int i = blockIdx.x * blockDim.x + threadIdx.x; i < n; i += gridDim.x * blockDim.x)
        m = fmaxf(m, fabsf(w[i]));
    for (int off = 32; off > 0; off >>= 1)
        m = fmaxf(m, __shfl_down(m, off));
    __shared__ float red[4];
    if ((threadIdx.x & 63) == 0) red[threadIdx.x >> 6] = m;
    __syncthreads();
    if (threadIdx.x == 0) {
        m = fmaxf(fmaxf(red[0], red[1]), fmaxf(red[2], red[3]));
        atomicMax(out, __float_as_uint(m));  // non-negative: uint order == float order
    }
}

// ---------------- kernel 2: ternary quantize + repack to [co][kk*128+ci] bf16 ----------------
__global__ __launch_bounds__(256) void quant_kernel(const float* __restrict__ w,
                                                    const float* __restrict__ wp,
                                                    const float* __restrict__ wn,
                                                    const unsigned* __restrict__ maxbits,
                                                    unsigned short* __restrict__ qw) {
    int idx = blockIdx.x * 256 + threadIdx.x;   // grid covers exactly 294912
    float t = 0.05f * __uint_as_float(maxbits[0]);
    float p = fabsf(wp[0]), nn = fabsf(wn[0]);
    float v = w[idx];
    float q = (v > t) ? p : ((v < -t) ? -nn : 0.0f);
    int co  = idx / KDIM;
    int rem = idx - co * KDIM;
    int ci  = rem / 9;
    int kk  = rem - ci * 9;            // kh*3+kw
    qw[co * KDIM + kk * CIN + ci] = f2bf(q);
}

// ---------------- kernel 3: x fp32 NCHW -> bf16 NHWC (x_t[b][h][w][ci]) ----------------
__global__ __launch_bounds__(256) void cast_nhwc_kernel(const float* __restrict__ x,
                                                        unsigned* __restrict__ xt_u32) {
    int b = blockIdx.x / HIN;
    int h = blockIdx.x - b * HIN;
    __shared__ float xs[CIN][57];
#pragma unroll
    for (int it = 0; it < 7; ++it) {
        int id = it * 256 + threadIdx.x;       // 1792 float4 chunks: 128 ci x 14
        int ci = id / 14;
        int wq = (id - ci * 14) * 4;
        float4 v = *(const float4*)(x + (((size_t)(b * CIN + ci)) * HIN + h) * WIN + wq);
        xs[ci][wq + 0] = v.x; xs[ci][wq + 1] = v.y;
        xs[ci][wq + 2] = v.z; xs[ci][wq + 3] = v.w;
    }
    __syncthreads();
#pragma unroll
    for (int it = 0; it < 7; ++it) {
        int id = it * 256 + threadIdx.x;       // 56 w x 32 chunks of 4 ci
        int w_ = id >> 5;
        int cq = (id & 31) * 4;
        unsigned u0 = (unsigned)f2bf(xs[cq + 0][w_]) | ((unsigned)f2bf(xs[cq + 1][w_]) << 16);
        unsigned u1 = (unsigned)f2bf(xs[cq + 2][w_]) | ((unsigned)f2bf(xs[cq + 3][w_]) << 16);
        uint2 val; val.x = u0; val.y = u1;
        *(uint2*)&xt_u32[((size_t)(b * HIN + h) * WIN + w_) * 64 + (id & 31) * 2] = val;
    }
}

// ---------------- kernel 4: implicit-GEMM MFMA conv, flat-N, async staging ----------------
// BM=128 (co), BN=128 (flat spatial), BK=32; grid = 2 mt x 64 b x 23 nt = 2944
__global__ __launch_bounds__(256, 3) void conv_mfma_kernel(const unsigned short* __restrict__ xt,
                                                           const unsigned short* __restrict__ qw,
                                                           const float* __restrict__ bias,
                                                           float* __restrict__ out) {
    int id = blockIdx.x;
    int nt = id % NTILES; id /= NTILES;
    int b  = id & 63;
    int mt = id >> 6;

    __shared__ __align__(16) unsigned short As[128 * 32];  // [row][32] no pad (DMA layout)
    __shared__ __align__(16) unsigned short Bs[128 * 32];

    int t    = threadIdx.x;
    int wave = t >> 6, lane = t & 63;
    int wm   = wave >> 1, wcol = wave & 1;
    int quad = lane >> 4, r16 = lane & 15;

    // ---- staging thread geometry: call c stages chunk p = c*256 + t ----
    // row = p>>2 (call0: 0..63, call1: 64..127), phys k-chunk = t&3,
    // logical k-chunk fetched = (t&3) ^ (row&3)  [XOR swizzle via source permutation]
    int r0 = t >> 2;
    int lc = (t & 3) ^ (r0 & 3);   // row+64 keeps row&3, so same for call 1

    const unsigned short* Ab0 = qw + (size_t)(mt * 128 + r0) * KDIM + lc * 8;
    const unsigned short* Ab1 = Ab0 + (size_t)64 * KDIM;

    unsigned n0 = nt * 128 + r0;       if (n0 > NSPAT - 1) n0 = NSPAT - 1;
    unsigned n1 = nt * 128 + 64 + r0;  if (n1 > NSPAT - 1) n1 = NSPAT - 1;
    unsigned oh0 = n0 / OWP, ow0 = n0 - oh0 * OWP;
    unsigned oh1 = n1 / OWP, ow1 = n1 - oh1 * OWP;
    const unsigned short* Bb0 = xt + ((size_t)(b * HIN + oh0) * WIN + ow0) * CIN + lc * 8;
    const unsigned short* Bb1 = xt + ((size_t)(b * HIN + oh1) * WIN + ow1) * CIN + lc * 8;

    char* AsD = (char*)As + wave * 1024;   // per-wave uniform LDS dest, call0
    char* BsD = (char*)Bs + wave * 1024;

    int swz = (quad ^ (r16 & 3)) * 8;      // phys chunk for logical chunk `quad` at row r16 (mod 4)

    f32x4 acc[4][4] = {};

#pragma unroll
    for (int slice = 0; slice < 9; ++slice) {
        int kh = slice / 3, kw = slice - (slice / 3) * 3;
#pragma unroll
        for (int cc = 0; cc < 4; ++cc) {
            int kc   = slice * 4 + cc;
            int offA = kc * 32;                          // shorts
            int offB = (kh * WIN + kw) * CIN + cc * 32;  // shorts

            gl_lds16(Ab0 + offA, AsD);
            gl_lds16(Ab1 + offA, AsD + 4096);
            gl_lds16(Bb0 + offB, BsD);
            gl_lds16(Bb1 + offB, BsD + 4096);
            __syncthreads();

            bf16x8 af[4], bfr[4];
#pragma unroll
            for (int i = 0; i < 4; ++i)
                af[i] = *(const bf16x8*)&As[(wm * 64 + i * 16 + r16) * 32 + swz];
#pragma unroll
            for (int j = 0; j < 4; ++j)
                bfr[j] = *(const bf16x8*)&Bs[(wcol * 64 + j * 16 + r16) * 32 + swz];
#pragma unroll
            for (int i = 0; i < 4; ++i)
#pragma unroll
                for (int j = 0; j < 4; ++j)
                    acc[i][j] = __builtin_amdgcn_mfma_f32_16x16x32_bf16(af[i], bfr[j], acc[i][j], 0, 0, 0);
            __syncthreads();
        }
    }

    // ---- epilogue: D row m = quad*4 + r, col n = r16 (verified R1) ----
#pragma unroll
    for (int j = 0; j < 4; ++j) {
        unsigned n = nt * 128 + wcol * 64 + j * 16 + r16;
        if (n < NSPAT) {
#pragma unroll
            for (int i = 0; i < 4; ++i) {
#pragma unroll
                for (int r = 0; r < 4; ++r) {
                    int co = mt * 128 + wm * 64 + i * 16 + quad * 4 + r;
                    out[(size_t)(b * COUT + co) * NSPAT + n] = acc[i][j][r] + bias[co];
                }
            }
        }
    }
}

extern "C" void kernel_launch(void* const* d_in, const int* in_sizes, int n_in,
                              void* d_out, int out_size, void* d_ws, size_t ws_size,
                              hipStream_t stream) {
    const float* x      = (const float*)d_in[0];
    const float* weight = (const float*)d_in[1];
    const float* bias   = (const float*)d_in[2];
    const float* wp     = (const float*)d_in[3];
    const float* wn     = (const float*)d_in[4];
    float* out          = (float*)d_out;

    // ws layout: [0,4) maxabs bits | [256,..) qw bf16 [256][1152] | [590080,..) x_t bf16 [64][56][56][128]
    unsigned*       ws_max = (unsigned*)d_ws;
    unsigned short* qw     = (unsigned short*)((char*)d_ws + 256);
    unsigned short* xt     = (unsigned short*)((char*)d_ws + 590080);

    hipMemsetAsync(d_ws, 0, 4, stream);
    maxabs_kernel<<<256, 256, 0, stream>>>(weight, ws_max, COUT * KDIM);
    quant_kernel<<<(COUT * KDIM) / 256, 256, 0, stream>>>(weight, wp, wn, ws_max, qw);
    cast_nhwc_kernel<<<BATCH * HIN, 256, 0, stream>>>(x, (unsigned*)xt);
    conv_mfma_kernel<<<2 * BATCH * NTILES, 256, 0, stream>>>(xt, qw, bias, out);
}

// Round 3
// 390.143 us; speedup vs baseline: 1.3696x; 1.1567x over previous
//
#include <hip/hip_runtime.h>
#include <hip/hip_bf16.h>

// Problem constants
#define BATCH 64
#define CIN   128
#define HIN   56
#define WIN   56
#define COUT  256
#define KSZ   3
#define OHP   54
#define OWP   54
#define NSPAT (OHP * OWP)          // 2916 flat spatial outputs per batch
#define NTILES 23                  // ceil(2916/128)
#define KDIM  (CIN * KSZ * KSZ)    // 1152

typedef short bf16x8 __attribute__((ext_vector_type(8)));
typedef float f32x4  __attribute__((ext_vector_type(4)));

static __device__ __forceinline__ unsigned short f2bf(float f) {
    unsigned v = __float_as_uint(f);
    v += 0x7FFFu + ((v >> 16) & 1u);
    return (unsigned short)(v >> 16);
}

static __device__ __forceinline__ void gl_lds16(const void* g, void* l) {
    __builtin_amdgcn_global_load_lds(
        (const __attribute__((address_space(1))) void*)g,
        (__attribute__((address_space(3))) void*)l, 16, 0, 0);
}

// ---------------- kernel 1: per-block max |w| (no atomics, no init needed) ----------------
__global__ __launch_bounds__(256) void maxabs_kernel(const float* __restrict__ w,
                                                     float* __restrict__ blockmax, int n) {
    float m = 0.f;
    for (int i = blockIdx.x * 256 + threadIdx.x; i < n; i += gridDim.x * 256)
        m = fmaxf(m, fabsf(w[i]));
    for (int off = 32; off > 0; off >>= 1)
        m = fmaxf(m, __shfl_down(m, off));
    __shared__ float red[4];
    if ((threadIdx.x & 63) == 0) red[threadIdx.x >> 6] = m;
    __syncthreads();
    if (threadIdx.x == 0)
        blockmax[blockIdx.x] = fmaxf(fmaxf(red[0], red[1]), fmaxf(red[2], red[3]));
}

// ---------------- kernel 2: finish max-reduce + ternary quantize + repack ----------------
// qw layout: [co][(kh*3+kw)*128 + ci] bf16
__global__ __launch_bounds__(256) void quant_kernel(const float* __restrict__ w,
                                                    const float* __restrict__ wp,
                                                    const float* __restrict__ wn,
                                                    const float* __restrict__ blockmax,
                                                    unsigned short* __restrict__ qw) {
    __shared__ float red[4];
    float m = blockmax[threadIdx.x];          // 256 partial maxima
    for (int off = 32; off > 0; off >>= 1)
        m = fmaxf(m, __shfl_down(m, off));
    if ((threadIdx.x & 63) == 0) red[threadIdx.x >> 6] = m;
    __syncthreads();
    float t = 0.05f * fmaxf(fmaxf(red[0], red[1]), fmaxf(red[2], red[3]));

    int idx = blockIdx.x * 256 + threadIdx.x;   // grid covers exactly 294912
    float p = fabsf(wp[0]), nn = fabsf(wn[0]);
    float v = w[idx];
    float q = (v > t) ? p : ((v < -t) ? -nn : 0.0f);
    int co  = idx / KDIM;
    int rem = idx - co * KDIM;
    int ci  = rem / 9;
    int kk  = rem - ci * 9;            // kh*3+kw
    qw[co * KDIM + kk * CIN + ci] = f2bf(q);
}

// ---------------- kernel 3: x fp32 NCHW -> bf16 NHWC (x_t[b][h][w][ci]) ----------------
__global__ __launch_bounds__(256) void cast_nhwc_kernel(const float* __restrict__ x,
                                                        unsigned* __restrict__ xt_u32) {
    int b = blockIdx.x / HIN;
    int h = blockIdx.x - b * HIN;
    __shared__ float xs[CIN][57];
#pragma unroll
    for (int it = 0; it < 7; ++it) {
        int id = it * 256 + threadIdx.x;       // 1792 float4 chunks: 128 ci x 14
        int ci = id / 14;
        int wq = (id - ci * 14) * 4;
        float4 v = *(const float4*)(x + (((size_t)(b * CIN + ci)) * HIN + h) * WIN + wq);
        xs[ci][wq + 0] = v.x; xs[ci][wq + 1] = v.y;
        xs[ci][wq + 2] = v.z; xs[ci][wq + 3] = v.w;
    }
    __syncthreads();
#pragma unroll
    for (int it = 0; it < 7; ++it) {
        int id = it * 256 + threadIdx.x;       // 56 w x 32 chunks of 4 ci
        int w_ = id >> 5;
        int cq = (id & 31) * 4;
        unsigned u0 = (unsigned)f2bf(xs[cq + 0][w_]) | ((unsigned)f2bf(xs[cq + 1][w_]) << 16);
        unsigned u1 = (unsigned)f2bf(xs[cq + 2][w_]) | ((unsigned)f2bf(xs[cq + 3][w_]) << 16);
        uint2 val; val.x = u0; val.y = u1;
        *(uint2*)&xt_u32[((size_t)(b * HIN + h) * WIN + w_) * 64 + (id & 31) * 2] = val;
    }
}

// ---------------- kernel 4: implicit-GEMM MFMA conv ----------------
// BM=128 (co), BN=128 (flat spatial), BK=64; 18 K-iters, 32 MFMA/iter.
// grid = 2944 = 8 XCD x 368; blocks sharing b pinned to one XCD (b%8 == blockIdx%8).
__global__ __launch_bounds__(256, 3) void conv_mfma_kernel(const unsigned short* __restrict__ xt,
                                                           const unsigned short* __restrict__ qw,
                                                           const float* __restrict__ bias,
                                                           float* __restrict__ out) {
    int xcd = blockIdx.x & 7;
    int k   = blockIdx.x >> 3;          // 0..367
    int g   = k / 46;                   // 0..7
    int r   = k - g * 46;               // 0..45
    int b   = g * 8 + xcd;
    int mt  = r / 23;
    int nt  = r - mt * 23;

    __shared__ __align__(16) unsigned short As[128 * 64];   // [row][64] rows = co
    __shared__ __align__(16) unsigned short Bs[128 * 64];   // [row][64] rows = flat n

    int t    = threadIdx.x;
    int wave = t >> 6, lane = t & 63;
    int wm   = wave >> 1, wcol = wave & 1;
    int quad = lane >> 4, r16 = lane & 15;

    // staging: call c stages chunk p = c*256 + t; row = p>>3 = c*32 + (t>>3),
    // phys chunk-in-row = t&7, fetched logical chunk = (t&7) ^ (row&7)  [XOR-8 swizzle]
    int row0 = t >> 3;                         // 0..31
    int lc   = (t & 7) ^ (row0 & 7);           // c*32 doesn't change row&7

    const unsigned short* Ab = qw + (size_t)(mt * 128 + row0) * KDIM + lc * 8;
    const unsigned short* Bb[4];
#pragma unroll
    for (int c = 0; c < 4; ++c) {
        unsigned n = nt * 128 + c * 32 + row0;
        if (n > NSPAT - 1) n = NSPAT - 1;
        unsigned oh = n / OWP, ow = n - oh * OWP;
        Bb[c] = xt + ((size_t)(b * HIN + oh) * WIN + ow) * CIN + lc * 8;
    }

    f32x4 acc[4][4] = {};

#pragma unroll
    for (int kk = 0; kk < 18; ++kk) {
        int slice = kk >> 1;
        int kh = slice / 3, kw = slice - kh * 3;
        int boff = (kh * WIN + kw) * CIN + (kk & 1) * 64;   // shorts
        int aoff = kk * 64;                                 // shorts

#pragma unroll
        for (int c = 0; c < 4; ++c) {
            gl_lds16(Ab + aoff + c * 32 * KDIM, (char*)As + c * 4096 + wave * 1024);
            gl_lds16(Bb[c] + boff,              (char*)Bs + c * 4096 + wave * 1024);
        }
        __syncthreads();

#pragma unroll
        for (int s = 0; s < 2; ++s) {
            int pc = ((s * 4 + quad) ^ (r16 & 7)) * 8;      // phys chunk offset (shorts)
            bf16x8 af[4], bfr[4];
#pragma unroll
            for (int i = 0; i < 4; ++i)
                af[i] = *(const bf16x8*)&As[(wm * 64 + i * 16 + r16) * 64 + pc];
#pragma unroll
            for (int j = 0; j < 4; ++j)
                bfr[j] = *(const bf16x8*)&Bs[(wcol * 64 + j * 16 + r16) * 64 + pc];
#pragma unroll
            for (int i = 0; i < 4; ++i)
#pragma unroll
                for (int j = 0; j < 4; ++j)
                    acc[i][j] = __builtin_amdgcn_mfma_f32_16x16x32_bf16(af[i], bfr[j], acc[i][j], 0, 0, 0);
        }
        __syncthreads();
    }

    // ---- epilogue: D row m = quad*4 + r, col n = r16 (layout verified R1) ----
#pragma unroll
    for (int i = 0; i < 4; ++i) {
        int co_base = mt * 128 + wm * 64 + i * 16 + quad * 4;
        float4 bv = *(const float4*)(bias + co_base);
#pragma unroll
        for (int j = 0; j < 4; ++j) {
            unsigned n = nt * 128 + wcol * 64 + j * 16 + r16;
            if (n < NSPAT) {
                out[(size_t)(b * COUT + co_base + 0) * NSPAT + n] = acc[i][j][0] + bv.x;
                out[(size_t)(b * COUT + co_base + 1) * NSPAT + n] = acc[i][j][1] + bv.y;
                out[(size_t)(b * COUT + co_base + 2) * NSPAT + n] = acc[i][j][2] + bv.z;
                out[(size_t)(b * COUT + co_base + 3) * NSPAT + n] = acc[i][j][3] + bv.w;
            }
        }
    }
}

extern "C" void kernel_launch(void* const* d_in, const int* in_sizes, int n_in,
                              void* d_out, int out_size, void* d_ws, size_t ws_size,
                              hipStream_t stream) {
    const float* x      = (const float*)d_in[0];
    const float* weight = (const float*)d_in[1];
    const float* bias   = (const float*)d_in[2];
    const float* wp     = (const float*)d_in[3];
    const float* wn     = (const float*)d_in[4];
    float* out          = (float*)d_out;

    // ws layout: [0,1024) blockmax fp32[256] | [1024,..) qw bf16 [256][1152]
    //            [590848,..) x_t bf16 [64][56][56][128]
    float*          bmax = (float*)d_ws;
    unsigned short* qw   = (unsigned short*)((char*)d_ws + 1024);
    unsigned short* xt   = (unsigned short*)((char*)d_ws + 590848);

    maxabs_kernel<<<256, 256, 0, stream>>>(weight, bmax, COUT * KDIM);
    quant_kernel<<<(COUT * KDIM) / 256, 256, 0, stream>>>(weight, wp, wn, bmax, qw);
    cast_nhwc_kernel<<<BATCH * HIN, 256, 0, stream>>>(x, (unsigned*)xt);
    conv_mfma_kernel<<<2 * BATCH * NTILES, 256, 0, stream>>>(xt, qw, bias, out);
}